// Round 7
// baseline (458.106 us; speedup 1.0000x reference)
//
#include <hip/hip_runtime.h>

#define HSZ 32
#define TSEQ 2048
#define NBATCH 256

typedef unsigned int v2u __attribute__((ext_vector_type(2)));

__device__ __forceinline__ float hw_exp2(float x) {
#if __has_builtin(__builtin_amdgcn_exp2f)
    return __builtin_amdgcn_exp2f(x);
#else
    return exp2f(x);
#endif
}

__device__ __forceinline__ float hw_rcp(float x) {
#if __has_builtin(__builtin_amdgcn_rcpf)
    return __builtin_amdgcn_rcpf(x);
#else
    return 1.0f / x;
#endif
}

__device__ __forceinline__ float readlane_f(float v, int lane) {
    return __uint_as_float(__builtin_amdgcn_readlane(__float_as_uint(v), lane));
}

// Direction-agnostic cross-half combine: returns v[lane&31] + v[(lane&31)+32]
// in ALL lanes, regardless of which way the swap moves halves. (Proven R2-R5.)
__device__ __forceinline__ float half_sum(float v) {
#if __has_builtin(__builtin_amdgcn_permlane32_swap)
    v2u r = __builtin_amdgcn_permlane32_swap(__float_as_uint(v), __float_as_uint(v), false, false);
    return __uint_as_float(r.x) + __uint_as_float(r.y);
#else
    return v + __shfl_xor(v, 32, 64);
#endif
}

// In-loop ArchVGPR pin: volatile => cannot be hoisted out of the loop;
// "+v" => the live-across-iterations value must sit in an arch VGPR (AGPR
// cannot satisfy "v"), killing the accvgpr_read-per-use tax. Emits NOTHING.
#define PIN(f) asm volatile("" : "+v"(f))

#define NL2E -1.44269504088896340736f   // -log2(e)

__global__ __launch_bounds__(64, 1) void lstm_last_kernel(
    const float* __restrict__ x,      // [B, T, 1]
    const float* __restrict__ W_ih,   // [4H, 1]
    const float* __restrict__ W_hh,   // [4H, H]
    const float* __restrict__ b_ih,   // [4H]
    const float* __restrict__ b_hh,   // [4H]
    float* __restrict__ out)          // [B, H]
{
    const int b    = blockIdx.x;
    const int l    = threadIdx.x;   // 0..63
    const int k    = l & 31;        // hidden unit index
    const int half = l >> 5;        // 0: rows (i_k, g_k); 1: rows (f_k, o_k)
    const int row0 = l;             // i_k (half0) or f_k (half1)
    const int row1 = l + 64;        // g_k (half0) or o_k (half1)

    __shared__ float x_lds[TSEQ + 4];

    // ---- one-time staging: x row into LDS (float4, coalesced) ----
    const float4* xrow4 = (const float4*)(x + (size_t)b * TSEQ);
    float4* xl4 = (float4*)x_lds;
    #pragma unroll
    for (int j = 0; j < (TSEQ / 4) / 64; ++j)   // 8 iters
        xl4[j * 64 + l] = xrow4[j * 64 + l];
    if (l == 0) x_lds[TSEQ] = 0.0f;

    // ---- one-time: weights, PRE-SCALED so every sigmoid is rcp(1+exp2(d)) ----
    // dot0 (i/f): scale -log2e. dot1: g (tanh=2*sigm(2x)-1) -> -2log2e; o -> -log2e.
    const float sc0 = NL2E;
    const float sc1 = half ? NL2E : 2.0f * NL2E;

    float w0[HSZ], w1[HSZ];
    #pragma unroll
    for (int j = 0; j < HSZ; j += 4) {
        float4 a  = *(const float4*)(W_hh + row0 * HSZ + j);
        float4 c4 = *(const float4*)(W_hh + row1 * HSZ + j);
        w0[j] = a.x * sc0;  w0[j+1] = a.y * sc0;  w0[j+2] = a.z * sc0;  w0[j+3] = a.w * sc0;
        w1[j] = c4.x * sc1; w1[j+1] = c4.y * sc1; w1[j+2] = c4.z * sc1; w1[j+3] = c4.w * sc1;
    }
    float wx0   = W_ih[row0] * sc0;
    float wx1   = W_ih[row1] * sc1;
    float bias0 = (b_ih[row0] + b_hh[row0]) * sc0;
    float bias1 = (b_ih[row1] + b_hh[row1]) * sc1;

    const float s1mul = half ? 1.0f : 2.0f;
    const float s1add = half ? 0.0f : -1.0f;

    float c  = 0.0f;   // cell state
    float hk = 0.0f;   // h_k valid in lanes 32..63

    __syncthreads();
    float xt = x_lds[0];

    #pragma unroll 1
    for (int t = 0; t < TSEQ; ++t) {
        // ---- pin all weight scalars into ArchVGPRs for this iteration ----
        #pragma unroll
        for (int j = 0; j < HSZ; ++j) { PIN(w0[j]); PIN(w1[j]); }
        PIN(wx0); PIN(wx1); PIN(bias0); PIN(bias1);

        // ---- broadcast h (lanes 32..63) into 32 wave-uniform SGPRs ----
        float hs[HSZ];
        #pragma unroll
        for (int j = 0; j < HSZ; ++j) hs[j] = readlane_f(hk, 32 + j);

        float xt_next = x_lds[t + 1];   // prefetch, latency hidden under dots

        // ---- two length-32 dots: v_fma_f32, VGPR weight x SGPR h (legal) ----
        float p00 = fmaf(wx0, xt, bias0), p01 = 0.f, p02 = 0.f, p03 = 0.f;
        float p10 = fmaf(wx1, xt, bias1), p11 = 0.f, p12 = 0.f, p13 = 0.f;
        #pragma unroll
        for (int j = 0; j < HSZ; j += 4) {
            p00 = fmaf(w0[j],   hs[j],   p00);
            p01 = fmaf(w0[j+1], hs[j+1], p01);
            p02 = fmaf(w0[j+2], hs[j+2], p02);
            p03 = fmaf(w0[j+3], hs[j+3], p03);
            p10 = fmaf(w1[j],   hs[j],   p10);
            p11 = fmaf(w1[j+1], hs[j+1], p11);
            p12 = fmaf(w1[j+2], hs[j+2], p12);
            p13 = fmaf(w1[j+3], hs[j+3], p13);
        }
        float d0 = (p00 + p01) + (p02 + p03);   // i (half0) / f (half1), pre-scaled
        float d1 = (p10 + p11) + (p12 + p13);   // g (half0) / o (half1), pre-scaled

        float a0 = hw_rcp(1.0f + hw_exp2(d0));                     // sigmoid(i/f)
        float a1 = fmaf(s1mul, hw_rcp(1.0f + hw_exp2(d1)), s1add); // tanh(g)/sigm(o)

        // half0 contributes i*g, half1 contributes f*c; cross-half SUM = c_new
        float v  = a0 * (half ? c : a1);
        float cn = half_sum(v);
        c = cn;

        float th = fmaf(2.0f, hw_rcp(1.0f + hw_exp2(cn * (2.0f * NL2E))), -1.0f); // tanh(c)
        hk = a1 * th;   // valid (o * tanh(c)) in lanes 32..63

        xt = xt_next;
    }

    if (half) out[b * HSZ + k] = hk;
}

extern "C" void kernel_launch(void* const* d_in, const int* in_sizes, int n_in,
                              void* d_out, int out_size, void* d_ws, size_t ws_size,
                              hipStream_t stream) {
    const float* x    = (const float*)d_in[0];
    const float* W_ih = (const float*)d_in[1];
    const float* W_hh = (const float*)d_in[2];
    const float* b_ih = (const float*)d_in[3];
    const float* b_hh = (const float*)d_in[4];
    float* out = (float*)d_out;

    lstm_last_kernel<<<NBATCH, 64, 0, stream>>>(x, W_ih, W_hh, b_ih, b_hh, out);
}